// Round 6
// baseline (374.813 us; speedup 1.0000x reference)
//
#include <hip/hip_runtime.h>

// FSMN depthwise strided FIR — cooperative LDS staging via global_load_lds.
// B=32, T=2000, D=512, L=R=20, strides=2.
//
// R5 post-mortem: ALL register-level pipelines (dist-2 queues R4, batched
// double-buffer R5) collapse to ~1 outstanding load/wave — the compiler
// scheduler serializes VMEM regardless of source order (m131 failure mode).
// 215us = 87 loads/wave x ~700cy x 63 waves/CU / 8 resident. Structural fix:
// async DMA staging (global_load_lds has no VGPR dest -> nothing to
// serialize; waits are explicit __syncthreads), compute reads LDS (~120cy).
//
// Geometry: block = 4 waves = 4 consecutive m-groups (16 m), one d-half,
// one batch. Union of all windows = x rows [2*m0b-40, 2*m0b+71] = 112
// consecutive rows (E/O parities interleaved), 1KB each (256 floats) ->
// 64KB LDS as 4 chunks x 32 rows, 2 buffers. Chunk c lives at buf rows
// (br & 63) — single-AND addressing. Schedule (verified row ranges):
//   prologue: stage c0+c1 (16 rows/wave); sync
//   t=0..11 (reads rows 8..55); sync; stage c2 (8 rows/wave)
//   t=12..15 (rows 32..63, chunk1 only); sync (DMA drained)
//   t=16..27 (rows 40..87); sync; stage c3 (4 rows/wave, rows 96..111
//             -> buf rows 32..47, disjoint from chunk2's 0..31)
//   t=28..31 (rows 64..95, chunk2 only); sync
//   t=32..40 (rows 72..110)
// __syncthreads drains vmcnt (DMA) AND lgkmcnt (pending ds_reads before a
// buffer is overwritten) — race-safe by construction.
//
// Spill ledger: R2 no-unroll (VGPR 64); R3 cap170 spill (VGPR 84);
// R4 cap256->128 clean; R5 cap512->256 clean. R6 live set ~100 fl4-equiv,
// lb(256,2) (cap 256). Tells: VGPR>150 or dur unchanged = trouble.

#define B_ 32
#define T_ 2000
#define D_ 512
#define S_ 1000   // T/2
#define M_ 4      // m-positions per thread (=> 8 output rows)

__device__ __forceinline__ float4 zf4() {
    float4 z; z.x = 0.f; z.y = 0.f; z.z = 0.f; z.w = 0.f; return z;
}

__device__ __forceinline__ void fma4(float4& a, const float4 f, const float4 w) {
    a.x = fmaf(f.x, w.x, a.x);
    a.y = fmaf(f.y, w.y, a.y);
    a.z = fmaf(f.z, w.z, a.z);
    a.w = fmaf(f.w, w.w, a.w);
}

// Async global->LDS DMA, 16B/lane x 64 lanes = one 1KB row per call.
// g: per-lane global address; l: wave-uniform LDS row base (HW adds lane*16).
__device__ __forceinline__ void gload_lds16(const float* g, float* l) {
    __builtin_amdgcn_global_load_lds(
        (const __attribute__((address_space(1))) void*)g,
        (__attribute__((address_space(3))) void*)l,
        16, 0, 0);
}

template<bool CHK>
__device__ __forceinline__ void fsmn_body(float* __restrict__ lds,
                                          const float* __restrict__ xb,
                                          const float* __restrict__ fb,
                                          float* __restrict__ ob,
                                          int m0, int R0, int lane, int mg)
{
    // Stage block-row br (x row R0+br) into LDS buf row (br & 63).
    auto stage = [&](int br) {
        float* l = lds + ((br & 63) << 8);
        const int xr = R0 + br;
        if (!CHK || (unsigned)xr < (unsigned)T_) {
            gload_lds16(xb + (size_t)xr * D_, l);     // xb already + lane*4
        } else {
            *(float4*)(l + lane * 4) = zf4();         // zero-fill pad rows
        }
    };
    auto ldrow = [&](int br) -> float4 {
        return *(const float4*)(lds + ((br & 63) << 8) + lane * 4);
    };
    auto ldF = [&](int t) -> float4 {
        return *(const float4*)(fb + (size_t)t * D_);
    };

    // ---- Prologue: stage chunks 0+1 (rows 0..63), 16 rows per wave ----
#pragma unroll
    for (int r = 0; r < 16; ++r) stage(mg * 16 + r);

    float4 qF0 = ldF(0), qF1 = ldF(1);                // filter queue, dist 2
    __syncthreads();                                  // c0+c1 ready

    // ---- Init register windows from LDS (E: br=8mg+2k, O: +1; k=0..3) ----
    float4 wE[M_], wO[M_], ae[M_], ao[M_];
#pragma unroll
    for (int m = 0; m < M_; ++m) {
        wE[m] = ldrow(8 * mg + 2 * m);
        wO[m] = ldrow(8 * mg + 2 * m + 1);
        ae[m] = zf4(); ao[m] = zf4();
    }

    // Step t (tap filt[t]); push-row: E br=8mg+2t+8, O br=8mg+2t+8±1.
    auto dostep = [&](int t) {
        const float4 fv = qF0;
        qF0 = qF1;
        qF1 = (t + 2 <= 40) ? ldF(t + 2) : zf4();
        if (t <= 20) {
#pragma unroll
            for (int m = 0; m < M_; ++m) { fma4(ae[m], fv, wE[m]); fma4(ao[m], fv, wO[m]); }
        } else {
#pragma unroll
            for (int m = 0; m < M_; ++m) { fma4(ao[m], fv, wE[m]); fma4(ae[m], fv, wO[m]); }
        }
        if (t < 40) {
#pragma unroll
            for (int m = 0; m < M_ - 1; ++m) wE[m] = wE[m + 1];
            wE[M_ - 1] = ldrow(8 * mg + 2 * t + 8);
            if (t != 20) {                            // O holds at junction
#pragma unroll
                for (int m = 0; m < M_ - 1; ++m) wO[m] = wO[m + 1];
                wO[M_ - 1] = ldrow(8 * mg + 2 * t + 8 + ((t < 20) ? 1 : -1));
            }
        }
    };

#pragma unroll
    for (int t = 0; t < 12; ++t) dostep(t);
    __syncthreads();                                  // chunk0 reads drained
#pragma unroll
    for (int r = 0; r < 8; ++r) stage(64 + mg * 8 + r);   // chunk2 -> buf0
#pragma unroll
    for (int t = 12; t < 16; ++t) dostep(t);
    __syncthreads();                                  // chunk2 DMA drained
#pragma unroll
    for (int t = 16; t < 28; ++t) dostep(t);
    __syncthreads();                                  // chunk1 reads drained
#pragma unroll
    for (int r = 0; r < 4; ++r) stage(96 + mg * 4 + r);   // chunk3 -> buf1[0:16]
#pragma unroll
    for (int t = 28; t < 32; ++t) dostep(t);
    __syncthreads();                                  // chunk3 DMA drained
#pragma unroll
    for (int t = 32; t <= 40; ++t) dostep(t);

    // ---- Store 2*M_ output rows (coalesced float4 across 64 lanes) ----
#pragma unroll
    for (int m = 0; m < M_; ++m) {
        if (!CHK || (m0 + m) < S_) {
            *(float4*)(ob + (size_t)(2 * (m0 + m))     * D_) = ae[m];
            *(float4*)(ob + (size_t)(2 * (m0 + m) + 1) * D_) = ao[m];
        }
    }
}

__global__ __launch_bounds__(256, 2) void fsmn_kernel(
    const float* __restrict__ x, const float* __restrict__ filt,
    float* __restrict__ out)
{
    __shared__ float lds[64 * 256];        // 64 KiB: 2 buffers x 32 rows x 1KB

    const int lane = threadIdx.x;          // 0..63
    const int mg   = threadIdx.y;          // 0..3 : m-group (one wave each)

    // XCD-chunked swizzle: 4032 blocks = 8 XCDs x 504 (bijective).
    const int bid  = blockIdx.x;
    const int xcd  = bid & 7;
    const int slot = bid >> 3;
    const int n    = xcd * 504 + slot;
    const int mb   = n % 63;               // 0..62 : m-block (16 m each)
    const int rest = n / 63;
    const int dh   = rest & 1;             // d-half
    const int b    = rest >> 1;            // batch

    const int m0b = mb * 16;
    const int m0  = m0b + mg * M_;
    const int d   = (dh * 64 + lane) * 4;
    const float* xb = x + (size_t)b * T_ * D_ + d;
    const float* fb = filt + d;
    float*       ob = out + (size_t)b * T_ * D_ + d;
    const int R0  = 2 * m0b - 40;          // x row of block-row 0

    // Interior iff all 112 staged rows and all stores valid: mb in [2,60].
    // NOTE: no early-return anywhere — all 256 threads reach every barrier;
    // tail waves (m0 >= S_) compute on zero-filled rows, stores guarded.
    if (mb >= 2 && mb <= 60) fsmn_body<false>(lds, xb, fb, ob, m0, R0, lane, mg);
    else                     fsmn_body<true >(lds, xb, fb, ob, m0, R0, lane, mg);
}

extern "C" void kernel_launch(void* const* d_in, const int* in_sizes, int n_in,
                              void* d_out, int out_size, void* d_ws, size_t ws_size,
                              hipStream_t stream) {
    const float* x    = (const float*)d_in[0];
    const float* filt = (const float*)d_in[1];
    float*       out  = (float*)d_out;

    dim3 block(64, 4, 1);
    // 63 m-blocks x 2 d-halves x 32 batches = 4032 blocks.
    dim3 grid(4032, 1, 1);
    hipLaunchKernelGGL(fsmn_kernel, grid, block, 0, stream, x, filt, out);
}

// Round 7
// 276.154 us; speedup vs baseline: 1.3573x; 1.3573x over previous
//
#include <hip/hip_runtime.h>

// FSMN depthwise strided FIR — R7: filter-in-LDS + ring-buffered x staging.
// B=32, T=2000, D=512, L=R=20, strides=2.
//
// R6 post-mortem: 236us. Per-block critical path ~42k cy, of which the
// 41 per-step GLOBAL filter loads (~300-500cy serial each) and the
// distance-1 DMA barriers are first-order. R7 moves the filter into LDS
// (ds_read_b128 with compile-time imm offset + dist-2 reg queue) and
// stages x chunks one full phase ahead of their drain barrier.
//
// Geometry: block = 4 waves (mg=0..3) x 16 m, one d-half, one batch.
// x rows br=0..110 (x row R0+br, R0=32*mb-40), 1KB each.
// LDS: filt[41 rows][1KB] at FOFF=0; x ring 64 rows (slot = br&63) at
// XOFF. Chunks of 16 rows, c=0..6. Phase p computes t=8p..8p+7 reading
// chunks p..p+2 (row span [2t, 2t+33]); stages chunk p+3 at phase start
// (slots of chunk p-1, whose reads ended in phase p-1 — fenced by the
// phase barrier; DMA drained by the NEXT barrier, one full phase later).
//   prologue: stage filt(41) + chunks 0..2 (23 DMA/wave); sync
//   p=0..4: [stage chunk p+3 (p<=3); 8 steps (9 at p=4, t=40 incl)];
//           sync between phases
// 105 KB LDS -> 1 block/CU; occupancy LDS-capped, so lb(256,1) gives the
// RA full slack (no cap-spill). Spill tell: FETCH in GB.
//
// Step semantics (unchanged since R4, refcheck'd): parity windows
//   t<=20: ae+=f[t]*wE, ao+=f[t]*wO;  t>=21: ao+=f[t]*wE, ae+=f[t]*wO.
//   E push br=8mg+2t+8; O push br=8mg+2t+9 (t<20) / +7 (20<t<40);
//   O holds at t=20.

#define B_ 32
#define T_ 2000
#define D_ 512
#define S_ 1000   // T/2
#define M_ 4      // m-positions per thread (=> 8 output rows)

#define FOFF 0            // filter base (floats): rows 0..40
#define XOFF (41 * 256)   // x ring base (floats): 64 rows
#define LDS_FLOATS (XOFF + 64 * 256)   // 105 KiB total

__device__ __forceinline__ float4 zf4() {
    float4 z; z.x = 0.f; z.y = 0.f; z.z = 0.f; z.w = 0.f; return z;
}

__device__ __forceinline__ void fma4(float4& a, const float4 f, const float4 w) {
    a.x = fmaf(f.x, w.x, a.x);
    a.y = fmaf(f.y, w.y, a.y);
    a.z = fmaf(f.z, w.z, a.z);
    a.w = fmaf(f.w, w.w, a.w);
}

// Async global->LDS DMA: 16B/lane x 64 lanes = one 1KB row per call.
// g: per-lane global address; l: wave-uniform LDS row base (HW adds lane*16).
__device__ __forceinline__ void gload_lds16(const float* g, float* l) {
    __builtin_amdgcn_global_load_lds(
        (const __attribute__((address_space(1))) void*)g,
        (__attribute__((address_space(3))) void*)l,
        16, 0, 0);
}

template<bool CHK>
__device__ __forceinline__ void fsmn_body(float* __restrict__ lds,
                                          const float* __restrict__ xb,
                                          const float* __restrict__ fb,
                                          float* __restrict__ ob,
                                          int m0, int R0, int lane, int mg)
{
    // ---- staging helpers (wave-uniform row index) ----
    auto stageX = [&](int br) {
        float* l = lds + XOFF + ((br & 63) << 8);
        const int xr = R0 + br;
        if (!CHK || (unsigned)xr < (unsigned)T_) {
            gload_lds16(xb + (size_t)xr * D_, l);     // xb already + lane*4
        } else {
            *(float4*)(l + lane * 4) = zf4();         // zero-fill pad rows
        }
    };
    auto stageF = [&](int fr) {                       // always in-bounds
        gload_lds16(fb + (size_t)fr * D_, lds + FOFF + (fr << 8));
    };
    // ---- LDS read helpers ----
    auto ldrow = [&](int br) -> float4 {              // x ring
        return *(const float4*)(lds + XOFF + ((br & 63) << 8) + lane * 4);
    };
    auto ldsF = [&](int t) -> float4 {                // filt row, imm offset
        return *(const float4*)(lds + FOFF + (t << 8) + lane * 4);
    };

    // ---- Prologue: stage filt (41 rows) + x chunks 0..2 (48 rows) ----
#pragma unroll
    for (int r = 0; r < 11; ++r) {                    // fr = 4r+mg <= 40
        const int fr = 4 * r + mg;
        if (fr <= 40) stageF(fr);
    }
#pragma unroll
    for (int r = 0; r < 12; ++r) stageX(4 * r + mg);  // br 0..47
    __syncthreads();                                  // all prologue DMA done

    // ---- Init windows (rows <= 31: chunks 0-1) + filter queue ----
    float4 wE[M_], wO[M_], ae[M_], ao[M_];
#pragma unroll
    for (int m = 0; m < M_; ++m) {
        wE[m] = ldrow(8 * mg + 2 * m);
        wO[m] = ldrow(8 * mg + 2 * m + 1);
        ae[m] = zf4(); ao[m] = zf4();
    }
    float4 qF0 = ldsF(0), qF1 = ldsF(1);              // dist-2 LDS queue

    // ---- One step (tap filt[t]); all t compile-time under unroll ----
    auto dostep = [&](int t) {
        const float4 fv = qF0;
        qF0 = qF1;
        qF1 = (t + 2 <= 40) ? ldsF(t + 2) : zf4();
        if (t <= 20) {
#pragma unroll
            for (int m = 0; m < M_; ++m) { fma4(ae[m], fv, wE[m]); fma4(ao[m], fv, wO[m]); }
        } else {
#pragma unroll
            for (int m = 0; m < M_; ++m) { fma4(ao[m], fv, wE[m]); fma4(ae[m], fv, wO[m]); }
        }
        if (t < 40) {
#pragma unroll
            for (int m = 0; m < M_ - 1; ++m) wE[m] = wE[m + 1];
            wE[M_ - 1] = ldrow(8 * mg + 2 * t + 8);
            if (t != 20) {                            // O holds at junction
#pragma unroll
                for (int m = 0; m < M_ - 1; ++m) wO[m] = wO[m + 1];
                wO[M_ - 1] = ldrow(8 * mg + 2 * t + 8 + ((t < 20) ? 1 : -1));
            }
        }
    };

    // ---- Phases p=0..4 ----
#pragma unroll
    for (int p = 0; p < 5; ++p) {
        if (p <= 3) {                                 // stage chunk p+3
#pragma unroll
            for (int r = 0; r < 4; ++r) stageX(16 * (p + 3) + 4 * r + mg);
        }
#pragma unroll
        for (int t = 8 * p; t < ((p == 4) ? 41 : 8 * p + 8); ++t) dostep(t);
        if (p < 4) __syncthreads();                   // drain DMA + fence reads
    }

    // ---- Store 2*M_ output rows (coalesced float4 across 64 lanes) ----
#pragma unroll
    for (int m = 0; m < M_; ++m) {
        if (!CHK || (m0 + m) < S_) {
            *(float4*)(ob + (size_t)(2 * (m0 + m))     * D_) = ae[m];
            *(float4*)(ob + (size_t)(2 * (m0 + m) + 1) * D_) = ao[m];
        }
    }
}

__global__ __launch_bounds__(256, 1) void fsmn_kernel(
    const float* __restrict__ x, const float* __restrict__ filt,
    float* __restrict__ out)
{
    __shared__ float lds[LDS_FLOATS];      // 105 KiB: filt 41KB + x ring 64KB

    const int lane = threadIdx.x;          // 0..63
    const int mg   = threadIdx.y;          // 0..3 : m-group (one wave each)

    // XCD-chunked swizzle: 4032 blocks = 8 XCDs x 504 (bijective).
    const int bid  = blockIdx.x;
    const int xcd  = bid & 7;
    const int slot = bid >> 3;
    const int n    = xcd * 504 + slot;
    const int mb   = n % 63;               // 0..62 : m-block (16 m each)
    const int rest = n / 63;
    const int dh   = rest & 1;             // d-half
    const int b    = rest >> 1;            // batch

    const int m0b = mb * 16;
    const int m0  = m0b + mg * M_;
    const int d   = (dh * 64 + lane) * 4;
    const float* xb = x + (size_t)b * T_ * D_ + d;
    const float* fb = filt + d;
    float*       ob = out + (size_t)b * T_ * D_ + d;
    const int R0  = 2 * m0b - 40;          // x row of block-row 0

    // Interior iff all rows br=0..110 valid and all stores valid: mb in [2,60].
    // No early-return — all 256 threads reach every barrier.
    if (mb >= 2 && mb <= 60) fsmn_body<false>(lds, xb, fb, ob, m0, R0, lane, mg);
    else                     fsmn_body<true >(lds, xb, fb, ob, m0, R0, lane, mg);
}

extern "C" void kernel_launch(void* const* d_in, const int* in_sizes, int n_in,
                              void* d_out, int out_size, void* d_ws, size_t ws_size,
                              hipStream_t stream) {
    const float* x    = (const float*)d_in[0];
    const float* filt = (const float*)d_in[1];
    float*       out  = (float*)d_out;

    dim3 block(64, 4, 1);
    // 63 m-blocks x 2 d-halves x 32 batches = 4032 blocks.
    dim3 grid(4032, 1, 1);
    hipLaunchKernelGGL(fsmn_kernel, grid, block, 0, stream, x, filt, out);
}